// Round 2
// baseline (22352.921 us; speedup 1.0000x reference)
//
#include <hip/hip_runtime.h>

typedef unsigned short u16;
typedef __attribute__((ext_vector_type(8))) short short8;
typedef __attribute__((ext_vector_type(4))) float floatx4;

#define B_   256
#define T_   512
#define E_   512
#define H_   1024
#define G4H  4096
#define KCAT 1536
#define M_   1024

__device__ __forceinline__ u16 f2bf(float f) {
    union { float f; unsigned u; } v; v.f = f;
    unsigned r = (v.u + 0x7fffu + ((v.u >> 16) & 1u)) >> 16;
    return (u16)r;
}
__device__ __forceinline__ float sigf(float x) {
    return __fdividef(1.0f, 1.0f + __expf(-x));
}
__device__ __forceinline__ float tanh_f(float x) {
    return 1.0f - __fdividef(2.0f, __expf(2.0f * x) + 1.0f);
}

// ---------------- prep kernels ----------------

__global__ void prep_emb(const int* __restrict__ x, const float* __restrict__ tab,
                         u16* __restrict__ emb) {
    int idx = (blockIdx.x * 256 + threadIdx.x) * 4;   // elem in [0, B*T*E)
    int row = idx >> 9;                               // / E_
    int e   = idx & 511;
    int xv  = x[row];
    float4 v = *(const float4*)(tab + (size_t)xv * E_ + e);
    ushort4 o; o.x = f2bf(v.x); o.y = f2bf(v.y); o.z = f2bf(v.z); o.w = f2bf(v.w);
    *(ushort4*)(emb + idx) = o;
}

__global__ void prep_wcat(const float* __restrict__ Whh, const float* __restrict__ Wih,
                          u16* __restrict__ wcat) {
    int idx = (blockIdx.x * 256 + threadIdx.x) * 4;   // [0, 4096*1536)
    int g = idx / KCAT;
    int k = idx - g * KCAT;
    const float* src = (k < H_) ? (Whh + (size_t)g * H_ + k)
                                : (Wih + (size_t)g * E_ + (k - H_));
    float4 v = *(const float4*)src;
    ushort4 o; o.x = f2bf(v.x); o.y = f2bf(v.y); o.z = f2bf(v.z); o.w = f2bf(v.w);
    *(ushort4*)(wcat + idx) = o;
}

__global__ void prep_fc1w(const float* __restrict__ src, u16* __restrict__ dst) {
    int idx = (blockIdx.x * 256 + threadIdx.x) * 4;   // [0, 1024*1024)
    float4 v = *(const float4*)(src + idx);
    ushort4 o; o.x = f2bf(v.x); o.y = f2bf(v.y); o.z = f2bf(v.z); o.w = f2bf(v.w);
    *(ushort4*)(dst + idx) = o;
}

__global__ void prep_bias(const float* __restrict__ bih, const float* __restrict__ bhh,
                          float* __restrict__ bias) {
    int i = blockIdx.x * 256 + threadIdx.x;           // [0, 4096)
    bias[i] = bih[i] + bhh[i];
}

__global__ void prep_state(const float* __restrict__ h0, u16* __restrict__ hbuf0) {
    int i = blockIdx.x * 256 + threadIdx.x;           // [0, B*H)
    hbuf0[i] = f2bf(h0[i]);
}

__global__ void zero_flags(int* __restrict__ f) {
    f[blockIdx.x * 256 + threadIdx.x] = 0;            // [0, 8*T_)
}

// ---------------- persistent LSTM ----------------
// 256 blocks x 512 threads, 1 block/CU (LDS-forced -> all co-resident).
// group g = blockIdx%8 owns batch rows [32g,32g+32); 32 blocks/group split
// 4096 gate-cols (128 per block; 16 per wave, weights register-resident).
// Per-group flag counters sync h exchange across steps (ping-pong h buffer).

__global__ __launch_bounds__(512, 2) void lstm_persist(
    const u16* __restrict__ emb, const u16* __restrict__ wcat,
    const float* __restrict__ bias, const float* __restrict__ c0,
    const int* __restrict__ x_index,
    u16* __restrict__ hbuf, float* __restrict__ hn, int* __restrict__ flags)
{
    // A tile: [32 rows][193 chunks pad][8 bf16]  (192 chunks = K=1536)
    __shared__ __align__(16) u16 Al[32 * 193 * 8];     // 98816 B
    __shared__ float Gl[4][32][33];                    // 16896 B

    const int bid = blockIdx.x;
    const int g   = bid & 7;          // sync/row group (XCD under %8 mapping)
    const int cb  = bid >> 3;         // 0..31 col-block within group
    const int hb0 = cb * 32;          // h-col base (32 h-cols per block)
    const int tid = threadIdx.x;
    const int row = tid >> 4;         // 0..31 staging/epilogue row
    const int ci  = tid & 15;
    const int grow = g * 32 + row;    // global batch row
    const int w    = tid >> 6;        // wave 0..7
    const int lane = tid & 63;
    const int lr   = lane & 15;
    const int lk   = lane >> 4;
    const int gate = w & 3;           // i,f,g,o
    const int hs   = w >> 2;          // col half (0/1): 16 h-cols each

    // ---- one-time: weight fragments into registers (48 x short8 = 192 VGPR) ----
    short8 bw[48];
    {
        const size_t gcol = (size_t)gate * H_ + hb0 + hs * 16 + lr;
        const u16* wp = wcat + gcol * KCAT + lk * 8;
        #pragma unroll
        for (int s = 0; s < 48; ++s)
            bw[s] = *(const short8*)(wp + s * 32);
    }
    // ---- one-time: c cells (2 per thread) ----
    const int col0 = hb0 + 2 * ci;    // local cols 2ci, 2ci+1
    float2 cc = *(const float2*)(c0 + (size_t)grow * H_ + col0);
    const int xi = x_index[grow];

    for (int t = 0; t < T_; ++t) {
        const u16* hread  = hbuf + (size_t)(t & 1) * (B_ * H_);
        u16*       hwrite = hbuf + (size_t)((t + 1) & 1) * (B_ * H_);

        // emb chunks (h-independent) before the flag spin
        {
            const u16* er = emb + ((size_t)grow * T_ + t) * E_;
            #pragma unroll
            for (int i = 8; i < 12; ++i) {
                int c = ci + 16 * i;                       // 128..191
                *(uint4*)&Al[((row * 193) + c) * 8] = *(const uint4*)(er + c * 8 - H_);
            }
        }
        if (t > 0) {
            if (tid == 0) {
                while (__hip_atomic_load(&flags[g * T_ + t - 1], __ATOMIC_ACQUIRE,
                                         __HIP_MEMORY_SCOPE_AGENT) < 32)
                    __builtin_amdgcn_s_sleep(2);
            }
            __syncthreads();
        }
        {
            const u16* hr = hread + (size_t)grow * H_;
            #pragma unroll
            for (int i = 0; i < 8; ++i) {
                int c = ci + 16 * i;                       // 0..127
                *(uint4*)&Al[((row * 193) + c) * 8] = *(const uint4*)(hr + c * 8);
            }
        }
        __syncthreads();

        // ---- MFMA: 48 k-steps x 2 row-tiles ----
        floatx4 a0 = {0.f, 0.f, 0.f, 0.f}, a1 = {0.f, 0.f, 0.f, 0.f};
        #pragma unroll
        for (int s = 0; s < 48; ++s) {
            short8 f0 = *(const short8*)&Al[(lr * 193 + s * 4 + lk) * 8];
            short8 f1 = *(const short8*)&Al[((16 + lr) * 193 + s * 4 + lk) * 8];
            a0 = __builtin_amdgcn_mfma_f32_16x16x32_bf16(f0, bw[s], a0, 0, 0, 0);
            a1 = __builtin_amdgcn_mfma_f32_16x16x32_bf16(f1, bw[s], a1, 0, 0, 0);
        }
        #pragma unroll
        for (int r = 0; r < 4; ++r) {
            Gl[gate][lk * 4 + r][hs * 16 + lr]      = a0[r];
            Gl[gate][16 + lk * 4 + r][hs * 16 + lr] = a1[r];
        }
        __syncthreads();

        // ---- epilogue: thread (row, ci) owns cols col0, col0+1 ----
        float hv[2];
        #pragma unroll
        for (int e = 0; e < 2; ++e) {
            int lc = 2 * ci + e;
            int gc = col0 + e;
            float gi = Gl[0][row][lc] + bias[gc];
            float gf = Gl[1][row][lc] + bias[H_ + gc];
            float gg = Gl[2][row][lc] + bias[2 * H_ + gc];
            float go = Gl[3][row][lc] + bias[3 * H_ + gc];
            float i_ = sigf(gi), f_ = sigf(gf), g_ = tanh_f(gg), o_ = sigf(go);
            float cprev = e ? cc.y : cc.x;
            float cn = f_ * cprev + i_ * g_;
            if (e) cc.y = cn; else cc.x = cn;
            hv[e] = o_ * tanh_f(cn);
        }
        unsigned packed = (unsigned)f2bf(hv[0]) | ((unsigned)f2bf(hv[1]) << 16);
        *(unsigned*)(hwrite + (size_t)grow * H_ + col0) = packed;
        if (xi == t) {
            hn[(size_t)grow * H_ + col0]     = hv[0];
            hn[(size_t)grow * H_ + col0 + 1] = hv[1];
        }
        __threadfence();
        __syncthreads();
        if (tid == 0)
            __hip_atomic_fetch_add(&flags[g * T_ + t], 1, __ATOMIC_RELEASE,
                                   __HIP_MEMORY_SCOPE_AGENT);
    }
}

// ---------------- tail ----------------

__global__ void hn_convert(const float* __restrict__ hn, u16* __restrict__ hnbf) {
    int i = blockIdx.x * 256 + threadIdx.x;  // [0, B*H)
    hnbf[i] = f2bf(hn[i]);
}

// z = tanh(hn @ fc1_w^T + b); grid (16, 4), 64x64 tile, K=1024
__global__ __launch_bounds__(256) void fc1_kernel(
    const u16* __restrict__ A, const u16* __restrict__ Bw,
    const float* __restrict__ bvec, float* __restrict__ z)
{
    __shared__ __align__(16) u16 Al[64 * 72];
    __shared__ __align__(16) u16 Bl[64 * 72];
    const int tid = threadIdx.x;
    const int rowbase = blockIdx.y * 64;
    const int colbase = blockIdx.x * 64;
    floatx4 acc[4] = {{0,0,0,0},{0,0,0,0},{0,0,0,0},{0,0,0,0}};
    const int w = tid >> 6, lane = tid & 63, lr = lane & 15, lk = lane >> 4;

    for (int s = 0; s < H_ / 64; ++s) {
        int k0 = s * 64;
        #pragma unroll
        for (int cc = 0; cc < 2; ++cc) {
            int c = tid + cc * 256;
            int row = c >> 3, kg = c & 7, kglob = k0 + kg * 8;
            *(uint4*)&Al[(row * 9 + kg) * 8] =
                *(const uint4*)(A + (size_t)(rowbase + row) * H_ + kglob);
            *(uint4*)&Bl[(row * 9 + kg) * 8] =
                *(const uint4*)(Bw + (size_t)(colbase + row) * H_ + kglob);
        }
        __syncthreads();
        #pragma unroll
        for (int ks = 0; ks < 2; ++ks) {
            short8 a = *(const short8*)&Al[((16 * w + lr) * 9 + ks * 4 + lk) * 8];
            #pragma unroll
            for (int q = 0; q < 4; ++q) {
                short8 b = *(const short8*)&Bl[((q * 16 + lr) * 9 + ks * 4 + lk) * 8];
                acc[q] = __builtin_amdgcn_mfma_f32_16x16x32_bf16(a, b, acc[q], 0, 0, 0);
            }
        }
        __syncthreads();
    }
    #pragma unroll
    for (int q = 0; q < 4; ++q) {
        int col = colbase + q * 16 + lr;
        float bb = bvec[col];
        #pragma unroll
        for (int r = 0; r < 4; ++r) {
            int row = rowbase + 16 * w + lk * 4 + r;
            z[(size_t)row * M_ + col] = tanh_f(acc[q][r] + bb);
        }
    }
}

// logits + log_softmax over O=2; one wave per batch row
__global__ __launch_bounds__(64) void fc2_softmax(
    const float* __restrict__ z, const float* __restrict__ wmat,
    const float* __restrict__ bvec, float* __restrict__ out)
{
    int bi = blockIdx.x;
    int lane = threadIdx.x;
    const float4* zr = (const float4*)(z + (size_t)bi * M_);
    const float4* w0 = (const float4*)(wmat);
    const float4* w1 = (const float4*)(wmat + M_);
    float s0 = 0.f, s1 = 0.f;
    for (int k = lane; k < M_ / 4; k += 64) {
        float4 zv = zr[k]; float4 a = w0[k]; float4 c = w1[k];
        s0 += zv.x * a.x + zv.y * a.y + zv.z * a.z + zv.w * a.w;
        s1 += zv.x * c.x + zv.y * c.y + zv.z * c.z + zv.w * c.w;
    }
    for (int off = 32; off; off >>= 1) {
        s0 += __shfl_down(s0, off);
        s1 += __shfl_down(s1, off);
    }
    if (lane == 0) {
        float l0 = s0 + bvec[0], l1 = s1 + bvec[1];
        float m = fmaxf(l0, l1);
        float lse = m + __logf(__expf(l0 - m) + __expf(l1 - m));
        out[bi * 2 + 0] = l0 - lse;
        out[bi * 2 + 1] = l1 - lse;
    }
}

// ---------------- launch ----------------

extern "C" void kernel_launch(void* const* d_in, const int* in_sizes, int n_in,
                              void* d_out, int out_size, void* d_ws, size_t ws_size,
                              hipStream_t stream)
{
    const int*   x       = (const int*)  d_in[0];
    const int*   x_index = (const int*)  d_in[1];
    const float* emb_t   = (const float*)d_in[2];
    const float* W_ih    = (const float*)d_in[3];
    const float* W_hh    = (const float*)d_in[4];
    const float* b_ih    = (const float*)d_in[5];
    const float* b_hh    = (const float*)d_in[6];
    const float* fc1_w   = (const float*)d_in[7];
    const float* fc1_b   = (const float*)d_in[8];
    const float* fc2_w   = (const float*)d_in[9];
    const float* fc2_b   = (const float*)d_in[10];
    const float* h0      = (const float*)d_in[11];
    const float* c0      = (const float*)d_in[12];
    float* out = (float*)d_out;

    char* p = (char*)d_ws;
    u16*   emb_bf = (u16*)p;   p += (size_t)B_ * T_ * E_ * 2;   // 134 MB
    u16*   wcat   = (u16*)p;   p += (size_t)G4H * KCAT * 2;     // 12.6 MB
    u16*   fc1wbf = (u16*)p;   p += (size_t)M_ * H_ * 2;        // 2 MB
    float* bias   = (float*)p; p += (size_t)G4H * 4;
    u16*   hbuf   = (u16*)p;   p += (size_t)2 * B_ * H_ * 2;    // ping-pong h
    float* hn     = (float*)p; p += (size_t)B_ * H_ * 4;
    u16*   hnbf   = (u16*)p;   p += (size_t)B_ * H_ * 2;
    float* zbuf   = (float*)p; p += (size_t)B_ * M_ * 4;
    int*   flags  = (int*)p;   p += (size_t)8 * T_ * 4;

    prep_emb  <<<65536, 256, 0, stream>>>(x, emb_t, emb_bf);
    prep_wcat <<<6144,  256, 0, stream>>>(W_hh, W_ih, wcat);
    prep_fc1w <<<1024,  256, 0, stream>>>(fc1_w, fc1wbf);
    prep_bias <<<16,    256, 0, stream>>>(b_ih, b_hh, bias);
    prep_state<<<1024,  256, 0, stream>>>(h0, hbuf);
    zero_flags<<<16,    256, 0, stream>>>(flags);

    lstm_persist<<<256, 512, 0, stream>>>(emb_bf, wcat, bias, c0, x_index,
                                          hbuf, hn, flags);

    hn_convert <<<1024, 256, 0, stream>>>(hn, hnbf);
    fc1_kernel <<<dim3(16, 4), 256, 0, stream>>>(hnbf, fc1wbf, fc1_b, zbuf);
    fc2_softmax<<<256, 64, 0, stream>>>(zbuf, fc2_w, fc2_b, out);
}

// Round 4
// 4070.775 us; speedup vs baseline: 5.4911x; 5.4911x over previous
//
#include <hip/hip_runtime.h>

typedef unsigned short u16;
typedef unsigned int u32;
typedef unsigned long long u64;
typedef __attribute__((ext_vector_type(8))) short short8;
typedef __attribute__((ext_vector_type(4))) float floatx4;
typedef __attribute__((ext_vector_type(4))) u32 u32x4;

#define B_   256
#define T_   512
#define E_   512
#define H_   1024
#define G4H  4096
#define KCAT 1536
#define M_   1024

__device__ __forceinline__ u16 f2bf(float f) {
    union { float f; unsigned u; } v; v.f = f;
    unsigned r = (v.u + 0x7fffu + ((v.u >> 16) & 1u)) >> 16;
    return (u16)r;
}
__device__ __forceinline__ float sigf(float x) {
    return __fdividef(1.0f, 1.0f + __expf(-x));
}
__device__ __forceinline__ float tanh_f(float x) {
    return 1.0f - __fdividef(2.0f, __expf(2.0f * x) + 1.0f);
}
// device-coherent 16B load (bypass L1/L2 -> always fresh at MALL)
__device__ __forceinline__ u32x4 load_sc(const u16* p) {
    u32x4 r;
    asm volatile("global_load_dwordx4 %0, %1, off sc0 sc1"
                 : "=v"(r) : "v"(p) : "memory");
    return r;
}

// ---------------- prep kernels ----------------

// rank rows by x_index descending (stable): perm[rank]=orig, sxi[rank]=xi
__global__ void sort_rows(const int* __restrict__ x_index,
                          int* __restrict__ perm, int* __restrict__ sxi) {
    __shared__ int xl[B_];
    int tid = threadIdx.x;
    xl[tid] = x_index[tid];
    __syncthreads();
    int mine = xl[tid], rank = 0;
    for (int j = 0; j < B_; ++j)
        rank += (xl[j] > mine) || (xl[j] == mine && j < tid);
    perm[rank] = tid;
    sxi[rank] = mine;
}

// emb_bf[srow][t][e] = bf16(tab[x[perm[srow]][t]][e])
__global__ void prep_emb(const int* __restrict__ x, const float* __restrict__ tab,
                         const int* __restrict__ perm, u16* __restrict__ emb) {
    int idx = (blockIdx.x * 256 + threadIdx.x) * 4;   // [0, B*T*E)
    int srow = idx >> 18;                             // / (T*E)
    int t    = (idx >> 9) & 511;
    int e    = idx & 511;
    int orig = perm[srow];
    int xv   = x[orig * T_ + t];
    float4 v = *(const float4*)(tab + (size_t)xv * E_ + e);
    ushort4 o; o.x = f2bf(v.x); o.y = f2bf(v.y); o.z = f2bf(v.z); o.w = f2bf(v.w);
    *(ushort4*)(emb + idx) = o;
}

__global__ void prep_wcat(const float* __restrict__ Whh, const float* __restrict__ Wih,
                          u16* __restrict__ wcat) {
    int idx = (blockIdx.x * 256 + threadIdx.x) * 4;   // [0, 4096*1536)
    int g = idx / KCAT;
    int k = idx - g * KCAT;
    const float* src = (k < H_) ? (Whh + (size_t)g * H_ + k)
                                : (Wih + (size_t)g * E_ + (k - H_));
    float4 v = *(const float4*)src;
    ushort4 o; o.x = f2bf(v.x); o.y = f2bf(v.y); o.z = f2bf(v.z); o.w = f2bf(v.w);
    *(ushort4*)(wcat + idx) = o;
}

__global__ void prep_fc1w(const float* __restrict__ src, u16* __restrict__ dst) {
    int idx = (blockIdx.x * 256 + threadIdx.x) * 4;
    float4 v = *(const float4*)(src + idx);
    ushort4 o; o.x = f2bf(v.x); o.y = f2bf(v.y); o.z = f2bf(v.z); o.w = f2bf(v.w);
    *(ushort4*)(dst + idx) = o;
}

__global__ void prep_bias(const float* __restrict__ bih, const float* __restrict__ bhh,
                          float* __restrict__ bias) {
    int i = blockIdx.x * 256 + threadIdx.x;
    bias[i] = bih[i] + bhh[i];
}

// sorted h0 (bf16) and c0 (f32)
__global__ void prep_state(const float* __restrict__ h0, const float* __restrict__ c0,
                           const int* __restrict__ perm,
                           u16* __restrict__ hbuf0, float* __restrict__ c0p) {
    int i = blockIdx.x * 256 + threadIdx.x;           // [0, B*H)
    int srow = i >> 10, col = i & 1023;
    int orig = perm[srow];
    hbuf0[i] = f2bf(h0[(size_t)orig * H_ + col]);
    c0p[i]   = c0[(size_t)orig * H_ + col];
}

__global__ void zero_flags(u32* __restrict__ f) {
    f[blockIdx.x * 256 + threadIdx.x] = 0;            // [0, 16*128)
}

// ---------------- persistent LSTM ----------------
// 256 blocks x 512 threads, 1 block/CU. grp = bid>>7 owns sorted rows
// [grp*128, grp*128+128); cb = bid&127 owns h-cols [8cb, 8cb+8) (32 gate-cols).
// Wave w owns 16-row tile w: stages A, computes 16x32 gates, epilogue, h-store.
// NO __syncthreads in the step loop; cross-block sync = per-(grp,tile,cb)
// monotonic version flags at agent scope. h exchanged via coherent (sc0 sc1)
// loads/stores; emb/weights are plain cached (read-only).

__global__ __launch_bounds__(512, 2) void lstm_persist(
    const u16* __restrict__ emb, const u16* __restrict__ wcat,
    const float* __restrict__ bias, const float* __restrict__ c0p,
    const int* __restrict__ sxi,
    u16* __restrict__ hbuf, float* __restrict__ hn, u32* __restrict__ flags)
{
    __shared__ __align__(16) u16 Wl[32 * 1544];       // 98,816 B  weights
    __shared__ __align__(16) u16 Al[8 * 2 * 1152];    // 36,864 B  per-wave A dbuf

    const int tid  = threadIdx.x;
    const int w    = tid >> 6;
    const int lane = tid & 63;
    const int lr   = lane & 15;
    const int lk   = lane >> 4;
    const int grp  = blockIdx.x >> 7;
    const int cb   = blockIdx.x & 127;
    const int erow = lane >> 2;
    const int e2   = (lane & 3) * 2;
    const int rowg = grp * 128 + w * 16 + erow;

    // ---- one-time: weights -> LDS (rows: [i x8 | f x8 | g x8 | o x8]) ----
    for (int i = tid; i < 32 * 192; i += 512) {
        int r = i / 192, kq = i - r * 192;
        int gcol = (r >> 3) * H_ + cb * 8 + (r & 7);
        *(u32x4*)&Wl[r * 1544 + kq * 8] =
            *(const u32x4*)(wcat + (size_t)gcol * KCAT + kq * 8);
    }
    __syncthreads();   // the ONLY block barrier

    const int tmax_w   = sxi[grp * 128 + w * 16];
    const int xi_lane  = sxi[rowg];
    float2 cc = *(const float2*)(c0p + (size_t)rowg * H_ + cb * 8 + e2);
    const float2 bI = *(const float2*)(bias + 0 * H_ + cb * 8 + e2);
    const float2 bF = *(const float2*)(bias + 1 * H_ + cb * 8 + e2);
    const float2 bG = *(const float2*)(bias + 2 * H_ + cb * 8 + e2);
    const float2 bO = *(const float2*)(bias + 3 * H_ + cb * 8 + e2);

    floatx4 acc0, acc1;
    auto MFMA_CHUNK = [&](int sbase, int kk) {
        #pragma unroll
        for (int ks = 0; ks < 2; ++ks) {
            short8 a  = *(const short8*)&Al[sbase + lr * 72 + (ks * 4 + lk) * 8];
            short8 b0 = *(const short8*)&Wl[lr * 1544 + kk + ks * 32 + lk * 8];
            short8 b1 = *(const short8*)&Wl[(16 + lr) * 1544 + kk + ks * 32 + lk * 8];
            acc0 = __builtin_amdgcn_mfma_f32_16x16x32_bf16(a, b0, acc0, 0, 0, 0);
            acc1 = __builtin_amdgcn_mfma_f32_16x16x32_bf16(a, b1, acc1, 0, 0, 0);
        }
    };
    auto STAGE_WRITE = [&](int slot, u32x4 v0, u32x4 v1) {
        int el = (w * 2 + slot) * 1152 + erow * 72 + (lane & 3) * 16;
        *(u32x4*)&Al[el]     = v0;
        *(u32x4*)&Al[el + 8] = v1;
    };

    for (int t = 0; t <= tmax_w; ++t) {
        const u16* hread  = hbuf + (size_t)(t & 1) * (B_ * H_);
        u16*       hwrite = hbuf + (size_t)((t + 1) & 1) * (B_ * H_);
        acc0 = (floatx4){0.f, 0.f, 0.f, 0.f};
        acc1 = (floatx4){0.f, 0.f, 0.f, 0.f};

        // ---- emb phase (k 1024..1535), plain cached loads, depth-4 ----
        {
            const u16* ebase = emb + ((size_t)rowg * T_ + t) * E_ + (lane & 3) * 16;
            u32x4 ev[4][2];
            #pragma unroll
            for (int c = 0; c < 4; ++c) {
                ev[c][0] = *(const u32x4*)(ebase + c * 64);
                ev[c][1] = *(const u32x4*)(ebase + c * 64 + 8);
            }
            #pragma unroll
            for (int ce = 0; ce < 8; ++ce) {
                STAGE_WRITE(ce & 1, ev[ce & 3][0], ev[ce & 3][1]);
                if (ce < 4) {
                    ev[ce & 3][0] = *(const u32x4*)(ebase + (ce + 4) * 64);
                    ev[ce & 3][1] = *(const u32x4*)(ebase + (ce + 4) * 64 + 8);
                }
                MFMA_CHUNK((w * 2 + (ce & 1)) * 1152, 1024 + ce * 64);
            }
        }

        // ---- wait for h_t (tile w of all 128 blocks in our group) ----
        if (t > 0) {
            u64* fp = (u64*)(flags + (grp * 8 + w) * 128);
            while (true) {
                u64 v = __hip_atomic_load(&fp[lane], __ATOMIC_RELAXED,
                                          __HIP_MEMORY_SCOPE_AGENT);
                if (__all(((u32)v >= (u32)t) && ((u32)(v >> 32) >= (u32)t))) break;
                __builtin_amdgcn_s_sleep(1);
            }
        }

        // ---- h phase (k 0..1023), coherent loads, 8-chunk pipeline ----
        {
            const u16* hbase = hread + (size_t)rowg * H_ + (lane & 3) * 16;
            u32x4 hv[8][2];
            #pragma unroll
            for (int c = 0; c < 8; ++c) {
                hv[c][0] = load_sc(hbase + c * 64);
                hv[c][1] = load_sc(hbase + c * 64 + 8);
            }
            #pragma unroll
            for (int c = 0; c < 16; ++c) {
                const int pend = (c < 8) ? 14 : (30 - 2 * c);
                asm volatile("s_waitcnt vmcnt(%0)" :: "i"(pend) : "memory");
                STAGE_WRITE(c & 1, hv[c & 7][0], hv[c & 7][1]);
                if (c < 8) {
                    hv[c][0] = load_sc(hbase + (c + 8) * 64);
                    hv[c][1] = load_sc(hbase + (c + 8) * 64 + 8);
                }
                MFMA_CHUNK((w * 2 + (c & 1)) * 1152, c * 64);
            }
        }

        // ---- epilogue: wave-internal LDS transpose (reuse A region) ----
        float* Gf = (float*)&Al[(w * 2) * 1152];      // [4 gates][16 rows][10]
        #pragma unroll
        for (int ct = 0; ct < 2; ++ct) {
            const floatx4 aa = ct ? acc1 : acc0;
            const int gate = ct * 2 + (lr >> 3);
            const int hc   = lr & 7;
            #pragma unroll
            for (int r = 0; r < 4; ++r)
                Gf[(gate * 16 + lk * 4 + r) * 10 + hc] = aa[r];
        }
        float2 g_i = *(float2*)&Gf[(0 * 16 + erow) * 10 + e2];
        float2 g_f = *(float2*)&Gf[(1 * 16 + erow) * 10 + e2];
        float2 g_g = *(float2*)&Gf[(2 * 16 + erow) * 10 + e2];
        float2 g_o = *(float2*)&Gf[(3 * 16 + erow) * 10 + e2];

        float i0 = sigf(g_i.x + bI.x), i1 = sigf(g_i.y + bI.y);
        float f0 = sigf(g_f.x + bF.x), f1 = sigf(g_f.y + bF.y);
        float q0 = tanh_f(g_g.x + bG.x), q1 = tanh_f(g_g.y + bG.y);
        float o0 = sigf(g_o.x + bO.x), o1 = sigf(g_o.y + bO.y);
        cc.x = f0 * cc.x + i0 * q0;
        cc.y = f1 * cc.y + i1 * q1;
        float h0f = o0 * tanh_f(cc.x);
        float h1f = o1 * tanh_f(cc.y);

        u32 packed = (u32)f2bf(h0f) | ((u32)f2bf(h1f) << 16);
        __hip_atomic_store((u32*)(hwrite + (size_t)rowg * H_ + cb * 8 + e2),
                           packed, __ATOMIC_RELAXED, __HIP_MEMORY_SCOPE_AGENT);
        if (xi_lane == t)
            *(float2*)(hn + (size_t)rowg * H_ + cb * 8 + e2) = make_float2(h0f, h1f);
        asm volatile("s_waitcnt vmcnt(0)" ::: "memory");
        if (lane == 0)
            __hip_atomic_store(flags + (grp * 8 + w) * 128 + cb, (u32)(t + 1),
                               __ATOMIC_RELAXED, __HIP_MEMORY_SCOPE_AGENT);
    }
}

// ---------------- tail ----------------

__global__ void hn_convert(const float* __restrict__ hn, u16* __restrict__ hnbf) {
    int i = blockIdx.x * 256 + threadIdx.x;
    hnbf[i] = f2bf(hn[i]);
}

__global__ __launch_bounds__(256) void fc1_kernel(
    const u16* __restrict__ A, const u16* __restrict__ Bw,
    const float* __restrict__ bvec, float* __restrict__ z)
{
    __shared__ __align__(16) u16 Als[64 * 72];
    __shared__ __align__(16) u16 Bls[64 * 72];
    const int tid = threadIdx.x;
    const int rowbase = blockIdx.y * 64;
    const int colbase = blockIdx.x * 64;
    floatx4 acc[4] = {{0,0,0,0},{0,0,0,0},{0,0,0,0},{0,0,0,0}};
    const int w = tid >> 6, lane = tid & 63, lr = lane & 15, lk = lane >> 4;

    for (int s = 0; s < H_ / 64; ++s) {
        int k0 = s * 64;
        #pragma unroll
        for (int cc2 = 0; cc2 < 2; ++cc2) {
            int c = tid + cc2 * 256;
            int row = c >> 3, kg = c & 7, kglob = k0 + kg * 8;
            *(u32x4*)&Als[(row * 9 + kg) * 8] =
                *(const u32x4*)(A + (size_t)(rowbase + row) * H_ + kglob);
            *(u32x4*)&Bls[(row * 9 + kg) * 8] =
                *(const u32x4*)(Bw + (size_t)(colbase + row) * H_ + kglob);
        }
        __syncthreads();
        #pragma unroll
        for (int ks = 0; ks < 2; ++ks) {
            short8 a = *(const short8*)&Als[((16 * w + lr) * 9 + ks * 4 + lk) * 8];
            #pragma unroll
            for (int q = 0; q < 4; ++q) {
                short8 b = *(const short8*)&Bls[((q * 16 + lr) * 9 + ks * 4 + lk) * 8];
                acc[q] = __builtin_amdgcn_mfma_f32_16x16x32_bf16(a, b, acc[q], 0, 0, 0);
            }
        }
        __syncthreads();
    }
    #pragma unroll
    for (int q = 0; q < 4; ++q) {
        int col = colbase + q * 16 + lr;
        float bb = bvec[col];
        #pragma unroll
        for (int r = 0; r < 4; ++r) {
            int row = rowbase + 16 * w + lk * 4 + r;
            z[(size_t)row * M_ + col] = tanh_f(acc[q][r] + bb);
        }
    }
}

__global__ __launch_bounds__(64) void fc2_softmax(
    const float* __restrict__ z, const float* __restrict__ wmat,
    const float* __restrict__ bvec, const int* __restrict__ perm,
    float* __restrict__ out)
{
    int bi = blockIdx.x;
    int lane = threadIdx.x;
    const float4* zr = (const float4*)(z + (size_t)bi * M_);
    const float4* w0 = (const float4*)(wmat);
    const float4* w1 = (const float4*)(wmat + M_);
    float s0 = 0.f, s1 = 0.f;
    for (int k = lane; k < M_ / 4; k += 64) {
        float4 zv = zr[k]; float4 a = w0[k]; float4 c = w1[k];
        s0 += zv.x * a.x + zv.y * a.y + zv.z * a.z + zv.w * a.w;
        s1 += zv.x * c.x + zv.y * c.y + zv.z * c.z + zv.w * c.w;
    }
    for (int off = 32; off; off >>= 1) {
        s0 += __shfl_down(s0, off);
        s1 += __shfl_down(s1, off);
    }
    if (lane == 0) {
        float l0 = s0 + bvec[0], l1 = s1 + bvec[1];
        float m = fmaxf(l0, l1);
        float lse = m + __logf(__expf(l0 - m) + __expf(l1 - m));
        int orig = perm[bi];
        out[orig * 2 + 0] = l0 - lse;
        out[orig * 2 + 1] = l1 - lse;
    }
}

// ---------------- launch ----------------

extern "C" void kernel_launch(void* const* d_in, const int* in_sizes, int n_in,
                              void* d_out, int out_size, void* d_ws, size_t ws_size,
                              hipStream_t stream)
{
    const int*   x       = (const int*)  d_in[0];
    const int*   x_index = (const int*)  d_in[1];
    const float* emb_t   = (const float*)d_in[2];
    const float* W_ih    = (const float*)d_in[3];
    const float* W_hh    = (const float*)d_in[4];
    const float* b_ih    = (const float*)d_in[5];
    const float* b_hh    = (const float*)d_in[6];
    const float* fc1_w   = (const float*)d_in[7];
    const float* fc1_b   = (const float*)d_in[8];
    const float* fc2_w   = (const float*)d_in[9];
    const float* fc2_b   = (const float*)d_in[10];
    const float* h0      = (const float*)d_in[11];
    const float* c0      = (const float*)d_in[12];
    float* out = (float*)d_out;

    char* p = (char*)d_ws;
    u16*   emb_bf = (u16*)p;   p += (size_t)B_ * T_ * E_ * 2;   // 134 MB
    u16*   wcat   = (u16*)p;   p += (size_t)G4H * KCAT * 2;     // 12.6 MB
    u16*   fc1wbf = (u16*)p;   p += (size_t)M_ * H_ * 2;        // 2 MB
    float* bias   = (float*)p; p += (size_t)G4H * 4;
    u16*   hbuf   = (u16*)p;   p += (size_t)2 * B_ * H_ * 2;    // ping-pong h
    float* c0p    = (float*)p; p += (size_t)B_ * H_ * 4;
    float* hn     = (float*)p; p += (size_t)B_ * H_ * 4;
    u16*   hnbf   = (u16*)p;   p += (size_t)B_ * H_ * 2;
    float* zbuf   = (float*)p; p += (size_t)B_ * M_ * 4;
    int*   perm   = (int*)p;   p += (size_t)B_ * 4;
    int*   sxi    = (int*)p;   p += (size_t)B_ * 4;
    u32*   flags  = (u32*)p;   p += (size_t)16 * 128 * 4;

    sort_rows <<<1,     256, 0, stream>>>(x_index, perm, sxi);
    prep_emb  <<<65536, 256, 0, stream>>>(x, emb_t, perm, emb_bf);  // FIX: full B*T*E coverage
    prep_wcat <<<6144,  256, 0, stream>>>(W_hh, W_ih, wcat);
    prep_fc1w <<<1024,  256, 0, stream>>>(fc1_w, fc1wbf);
    prep_bias <<<16,    256, 0, stream>>>(b_ih, b_hh, bias);
    prep_state<<<1024,  256, 0, stream>>>(h0, c0, perm, hbuf, c0p);
    zero_flags<<<8,     256, 0, stream>>>(flags);

    lstm_persist<<<256, 512, 0, stream>>>(emb_bf, wcat, bias, c0p, sxi,
                                          hbuf, hn, flags);

    hn_convert <<<1024, 256, 0, stream>>>(hn, hnbf);
    fc1_kernel <<<dim3(16, 4), 256, 0, stream>>>(hnbf, fc1wbf, fc1_b, zbuf);
    fc2_softmax<<<256, 64, 0, stream>>>(zbuf, fc2_w, fc2_b, perm, out);
}